// Round 14
// baseline (545.870 us; speedup 1.0000x reference)
//
#include <hip/hip_runtime.h>
#include <hip/hip_bf16.h>
#include <cstdint>
#include <cstddef>

typedef __attribute__((ext_vector_type(8))) short short8;
typedef __attribute__((ext_vector_type(4))) float floatx4;
typedef __attribute__((ext_vector_type(4))) unsigned short ushort4e;

#define B_   4
#define S_   2048
#define D_   1024
#define H_   16
#define DK_  64
#define DFF_ 4096
#define MTOT (B_ * S_)   // 8192
#define QKVLD 3072       // fused qkv row stride

__device__ __forceinline__ float bf2f(unsigned short u) {
    union { unsigned int i; float f; } v; v.i = ((unsigned int)u) << 16; return v.f;
}
__device__ __forceinline__ unsigned short f2bf(float f) {
    union { float f; unsigned int i; } v; v.f = f;
    unsigned int u = v.i;
    u += 0x7fffu + ((u >> 16) & 1u);   // RNE
    return (unsigned short)(u >> 16);
}
__device__ __forceinline__ void async_cp16(const void* g, void* l) {
    __builtin_amdgcn_global_load_lds(
        (const __attribute__((address_space(1))) unsigned int*)g,
        (__attribute__((address_space(3))) unsigned int*)l,
        16, 0, 0);
}
__device__ __forceinline__ void gbar() {
    asm volatile("" ::: "memory");
    __builtin_amdgcn_s_barrier();
    asm volatile("" ::: "memory");
}

__device__ __forceinline__ void cvt8(const void* src, unsigned short* dst, int i, int fl) {
    if (fl) {
        const floatx4* s = (const floatx4*)src;
        floatx4 a = s[i * 2], b = s[i * 2 + 1];
        short8 o;
        o[0] = (short)f2bf(a[0]); o[1] = (short)f2bf(a[1]);
        o[2] = (short)f2bf(a[2]); o[3] = (short)f2bf(a[3]);
        o[4] = (short)f2bf(b[0]); o[5] = (short)f2bf(b[1]);
        o[6] = (short)f2bf(b[2]); o[7] = (short)f2bf(b[3]);
        ((short8*)dst)[i] = o;
    } else {
        ((short8*)dst)[i] = ((const short8*)src)[i];
    }
}

// --------------------------- merged dtype probe + small-tensor convert ----
__global__ void probe_small(const unsigned short* __restrict__ x, int* flag,
                            const void* b1, const void* b2, const void* g1,
                            const void* be1, const void* g2, const void* be2,
                            unsigned short* db1, unsigned short* db2, unsigned short* dg1,
                            unsigned short* dbe1, unsigned short* dg2, unsigned short* dbe2) {
    __shared__ float red[4];
    __shared__ int flagS;
    const int tid = threadIdx.x;
    float mx = 0.f;
    #pragma unroll
    for (int i = 0; i < 16; i++) {
        float v = fabsf(bf2f(x[tid * 16 + i]));
        if (v != v) v = 1e30f;
        mx = fmaxf(mx, v);
    }
    #pragma unroll
    for (int off = 32; off > 0; off >>= 1) mx = fmaxf(mx, __shfl_down(mx, off));
    if ((tid & 63) == 0) red[tid >> 6] = mx;
    __syncthreads();
    if (tid == 0) {
        float m = fmaxf(fmaxf(red[0], red[1]), fmaxf(red[2], red[3]));
        int f = (m > 50.f) ? 1 : 0;
        *flag = f;
        flagS = f;
    }
    __syncthreads();
    const int fl = flagS;
    for (int i = tid; i < 1152; i += 256) {
        if (i < 512)       cvt8(b1,  db1,  i,        fl);
        else if (i < 640)  cvt8(b2,  db2,  i - 512,  fl);
        else if (i < 768)  cvt8(g1,  dg1,  i - 640,  fl);
        else if (i < 896)  cvt8(be1, dbe1, i - 768,  fl);
        else if (i < 1024) cvt8(g2,  dg2,  i - 896,  fl);
        else               cvt8(be2, dbe2, i - 1024, fl);
    }
}

// --------------------------------- merged weight convert (qkvo+w1+w2) ----
__global__ void cvt_all(const void* s0, const void* s1, const void* s2, const void* s3,
                        const void* w1, const void* w2,
                        unsigned short* __restrict__ dq,
                        unsigned short* __restrict__ dw1,
                        unsigned short* __restrict__ dw2,
                        const int* __restrict__ flag) {
    const int bid = blockIdx.x;
    const int fl  = *flag;
    if (bid < 2048) {
        const int t = bid >> 9;
        const int i = (bid & 511) * 256 + threadIdx.x;
        const void* s = (t == 0) ? s0 : (t == 1) ? s1 : (t == 2) ? s2 : s3;
        cvt8(s, dq + (size_t)t * (D_ * D_), i, fl);
    } else if (bid < 4096) {
        const int i = (bid - 2048) * 256 + threadIdx.x;
        cvt8(w1, dw1, i, fl);
    } else {
        const int i = (bid - 4096) * 256 + threadIdx.x;
        cvt8(w2, dw2, i, fl);
    }
}

// ---------------------------------------------------------------- GEMM ----
// 128x128 kernel (qkv / wo / ffn2).  XCD-chunk swizzle; perfect grid
// balance: qkv (24,64)=1536=6/CU, wo/ffn2 (8,64)=512=2/CU.
#define BM 128
#define BN 128
#define BK 64

template<int RELU, int HAS_BIAS, int RES_MODE, int OUT_MODE>
__global__ __launch_bounds__(256)
void gemm_bt(const unsigned short* __restrict__ A, int lda,
             const unsigned short* __restrict__ W, int ldw,
             const unsigned short* __restrict__ bias,
             const void* resid,
             void* out,
             int M, int N, int K,
             const int* __restrict__ flagp)
{
    __shared__ unsigned short As[BM * BK];
    __shared__ unsigned short Bs[BN * BK];

    const int tid  = threadIdx.x;
    const int lane = tid & 63;
    const int wave = tid >> 6;
    const int wm = wave >> 1;
    const int wn = wave & 1;
    const int lr = lane & 15;
    const int lq = lane >> 4;

    // bijective XCD-chunk swizzle (nwg % 8 == 0 for all call sites)
    const int nwg     = gridDim.x * gridDim.y;
    const int flat    = blockIdx.y * gridDim.x + blockIdx.x;
    const int logical = (flat & 7) * (nwg >> 3) + (flat >> 3);
    const int m0 = (logical / gridDim.x) * BM;
    const int n0 = (logical % gridDim.x) * BN;

    int fl = 1;
    if (RES_MODE == 3 || OUT_MODE == 2) fl = *flagp;

    floatx4 acc[4][4];
    #pragma unroll
    for (int i = 0; i < 4; i++)
        #pragma unroll
        for (int j = 0; j < 4; j++)
            acc[i][j] = (floatx4){0.f, 0.f, 0.f, 0.f};

    const int lrow = lane >> 3;                       // 0..7
    const int swz  = ((lane & 7) ^ lrow) * 8;         // swizzled col chunk
    const int rx   = lr & 7;
    const int p0   = ((lq)     ^ rx) * 8;             // kk=0 chunk = lq
    const int p1   = ((4 + lq) ^ rx) * 8;             // kk=32 chunk = 4+lq

    for (int k0 = 0; k0 < K; k0 += BK) {
        #pragma unroll
        for (int t = 0; t < 4; t++) {
            const int row = wave * 32 + t * 8;
            async_cp16(A + (size_t)(m0 + row + lrow) * lda + k0 + swz, &As[row * BK]);
            async_cp16(W + (size_t)(n0 + row + lrow) * ldw + k0 + swz, &Bs[row * BK]);
        }
        __syncthreads();
        #pragma unroll
        for (int kk = 0; kk < 2; kk++) {
            const int pos = kk ? p1 : p0;
            short8 af[4], bfr[4];
            #pragma unroll
            for (int i = 0; i < 4; i++) {
                af[i]  = *(const short8*)(&As[(wm * 64 + i * 16 + lr) * BK + pos]);
                bfr[i] = *(const short8*)(&Bs[(wn * 64 + i * 16 + lr) * BK + pos]);
            }
            #pragma unroll
            for (int i = 0; i < 4; i++)
                #pragma unroll
                for (int j = 0; j < 4; j++)
                    acc[i][j] = __builtin_amdgcn_mfma_f32_16x16x32_bf16(
                                    af[i], bfr[j], acc[i][j], 0, 0, 0);
        }
        __syncthreads();
    }

    #pragma unroll
    for (int i = 0; i < 4; i++) {
        #pragma unroll
        for (int j = 0; j < 4; j++) {
            const int col = n0 + wn * 64 + j * 16 + lr;
            const float bv = HAS_BIAS ? bf2f(bias[col]) : 0.f;
            #pragma unroll
            for (int r = 0; r < 4; r++) {
                const int row = m0 + wm * 64 + i * 16 + lq * 4 + r;
                const size_t idx = (size_t)row * N + col;
                float vvv = acc[i][j][r] + bv;
                if (RES_MODE == 1) vvv += bf2f(((const unsigned short*)resid)[idx]);
                if (RES_MODE == 2) vvv += ((const float*)resid)[idx];
                if (RES_MODE == 3) vvv += fl ? ((const float*)resid)[idx]
                                             : bf2f(((const unsigned short*)resid)[idx]);
                if (RELU) vvv = fmaxf(vvv, 0.f);
                if (OUT_MODE == 1)      ((float*)out)[idx] = vvv;
                else if (OUT_MODE == 0) ((unsigned short*)out)[idx] = f2bf(vvv);
                else { if (fl) ((float*)out)[idx] = vvv;
                       else    ((unsigned short*)out)[idx] = f2bf(vvv); }
            }
        }
    }
}

// -------------------------------------------- 256x256 GEMM (ffn1 only) --
// R7-verified configuration; ffn1 grid (8,32)=256 blocks = exactly 1/CU.
#define GBM 256
#define GBN 256
#define GBK 64

template<int RELU, int HAS_BIAS>
__global__ __launch_bounds__(512, 2)
void gemm256_bt(const unsigned short* __restrict__ A, int lda,
                const unsigned short* __restrict__ W, int ldw,
                const unsigned short* __restrict__ bias,
                unsigned short* __restrict__ out,
                int M, int N, int K)
{
    __shared__ unsigned short As[2][GBM * GBK];   // 64 KB
    __shared__ unsigned short Bs[2][GBN * GBK];   // 64 KB

    const int tid  = threadIdx.x;
    const int lane = tid & 63;
    const int wave = tid >> 6;       // 0..7
    const int wm   = wave >> 2;      // 0..1  -> rows wm*128
    const int wn   = wave & 3;       // 0..3  -> cols wn*64
    const int lr   = lane & 15;
    const int lq   = lane >> 4;

    // bijective XCD-chunk swizzle (nwg = 256, % 8 == 0)
    const int nwg     = gridDim.x * gridDim.y;
    const int flat    = blockIdx.y * gridDim.x + blockIdx.x;
    const int logical = (flat & 7) * (nwg >> 3) + (flat >> 3);
    const int m0 = (logical / gridDim.x) * GBM;
    const int n0 = (logical % gridDim.x) * GBN;

    const int lrow = lane >> 3;                   // 0..7
    const int schk = ((lane & 7) ^ lrow) * 8;     // pre-swizzled source chunk
    const int rx   = lr & 7;
    const int fp0  = ((lq)     ^ rx) * 8;         // kk=0 frag chunk
    const int fp1  = ((4 + lq) ^ rx) * 8;         // kk=32 frag chunk

    floatx4 acc[8][4];
    #pragma unroll
    for (int i = 0; i < 8; i++)
        #pragma unroll
        for (int j = 0; j < 4; j++)
            acc[i][j] = (floatx4){0.f, 0.f, 0.f, 0.f};

    const int nkt = K / GBK;

    // prologue: stage tile 0 into buffer 0, full drain (once)
    #pragma unroll
    for (int g = 0; g < 4; g++) {
        async_cp16(A + (size_t)(m0 + g * 64 + wave * 8 + lrow) * lda + schk,
                   &As[0][g * 4096 + wave * 512]);
        async_cp16(W + (size_t)(n0 + g * 64 + wave * 8 + lrow) * ldw + schk,
                   &Bs[0][g * 4096 + wave * 512]);
    }
    asm volatile("s_waitcnt vmcnt(0)" ::: "memory");
    __syncthreads();

    for (int t = 0; t < nkt; ++t) {
        const int cur   = t & 1;
        const int knext = (t + 1) * GBK;
        const bool more = (t + 1 < nkt);
        short8 bfr[4][2];

        #pragma unroll
        for (int p = 0; p < 4; ++p) {
            short8 af[2][2];
            #pragma unroll
            for (int ii = 0; ii < 2; ii++)
                #pragma unroll
                for (int kk = 0; kk < 2; kk++)
                    af[ii][kk] = *(const short8*)
                        &As[cur][(wm * 128 + p * 32 + ii * 16 + lr) * GBK + (kk ? fp1 : fp0)];
            if (p == 0) {
                #pragma unroll
                for (int j = 0; j < 4; j++)
                    #pragma unroll
                    for (int kk = 0; kk < 2; kk++)
                        bfr[j][kk] = *(const short8*)
                            &Bs[cur][(wn * 64 + j * 16 + lr) * GBK + (kk ? fp1 : fp0)];
                if (more) {
                    #pragma unroll
                    for (int g = 0; g < 4; g++)
                        async_cp16(A + (size_t)(m0 + g * 64 + wave * 8 + lrow) * lda + knext + schk,
                                   &As[cur ^ 1][g * 4096 + wave * 512]);
                }
            }
            if (p == 1 && more) {
                #pragma unroll
                for (int g = 0; g < 4; g++)
                    async_cp16(W + (size_t)(n0 + g * 64 + wave * 8 + lrow) * ldw + knext + schk,
                               &Bs[cur ^ 1][g * 4096 + wave * 512]);
            }
            if (p == 3) asm volatile("s_waitcnt vmcnt(0)" ::: "memory");
            gbar();
            __builtin_amdgcn_s_setprio(1);
            #pragma unroll
            for (int kk = 0; kk < 2; kk++)
                #pragma unroll
                for (int ii = 0; ii < 2; ii++)
                    #pragma unroll
                    for (int j = 0; j < 4; j++)
                        acc[p * 2 + ii][j] = __builtin_amdgcn_mfma_f32_16x16x32_bf16(
                                                 af[ii][kk], bfr[j][kk],
                                                 acc[p * 2 + ii][j], 0, 0, 0);
            __builtin_amdgcn_s_setprio(0);
            gbar();
        }
    }

    #pragma unroll
    for (int i = 0; i < 8; i++) {
        #pragma unroll
        for (int j = 0; j < 4; j++) {
            const int col = n0 + wn * 64 + j * 16 + lr;
            const float bv = HAS_BIAS ? bf2f(bias[col]) : 0.f;
            #pragma unroll
            for (int r = 0; r < 4; r++) {
                const int row = m0 + wm * 128 + i * 16 + lq * 4 + r;
                float vvv = acc[i][j][r] + bv;
                if (RELU) vvv = fmaxf(vvv, 0.f);
                out[(size_t)row * N + col] = f2bf(vvv);
            }
        }
    }
}

// ------------------------------------------------------------- LayerNorm --
template<int IN_MODE>   // 1 = f32, 2 = flag ? f32 : bf16
__global__ __launch_bounds__(256)
void ln_kernel(const void* __restrict__ Xv,
               const unsigned short* __restrict__ g,
               const unsigned short* __restrict__ be,
               unsigned short* __restrict__ out,
               const int* __restrict__ flagp)
{
    const int row = blockIdx.x;
    const int tid = threadIdx.x;
    int fl = 1;
    if (IN_MODE == 2) fl = *flagp;
    float x4[4];
    if (IN_MODE == 1 || fl) {
        const float* X = (const float*)Xv + (size_t)row * D_ + tid * 4;
        floatx4 t = *(const floatx4*)X;
        x4[0] = t[0]; x4[1] = t[1]; x4[2] = t[2]; x4[3] = t[3];
    } else {
        const unsigned short* X = (const unsigned short*)Xv + (size_t)row * D_ + tid * 4;
        ushort4e u = *(const ushort4e*)X;
        #pragma unroll
        for (int i = 0; i < 4; i++) x4[i] = bf2f(u[i]);
    }
    float s1 = x4[0] + x4[1] + x4[2] + x4[3];
    float s2 = x4[0]*x4[0] + x4[1]*x4[1] + x4[2]*x4[2] + x4[3]*x4[3];
    #pragma unroll
    for (int off = 32; off > 0; off >>= 1) {
        s1 += __shfl_down(s1, off);
        s2 += __shfl_down(s2, off);
    }
    __shared__ float r1[4], r2[4];
    const int wv = tid >> 6;
    if ((tid & 63) == 0) { r1[wv] = s1; r2[wv] = s2; }
    __syncthreads();
    s1 = r1[0] + r1[1] + r1[2] + r1[3];
    s2 = r2[0] + r2[1] + r2[2] + r2[3];
    const float mean = s1 * (1.0f / D_);
    const float var  = (s2 - (float)D_ * mean * mean) * (1.0f / (D_ - 1));
    const float rstd = rsqrtf(var + 1e-9f);

    ushort4e o4;
    #pragma unroll
    for (int i = 0; i < 4; i++) {
        const float gv = bf2f(g[tid * 4 + i]);
        const float bv = bf2f(be[tid * 4 + i]);
        o4[i] = f2bf(gv * (x4[i] - mean) * rstd + bv);
    }
    *(ushort4e*)(out + (size_t)row * D_ + tid * 4) = o4;
}

// -------------------------------------------------- V transpose per head --
__global__ __launch_bounds__(256)
void vtrans(const unsigned short* __restrict__ V, int ldv,
            unsigned short* __restrict__ Vt)
{
    __shared__ unsigned short t[64 * 72];
    const int tid = threadIdx.x;
    const int kt  = blockIdx.x * 64;
    const int bh  = blockIdx.y;
    const int b   = bh >> 4, h = bh & 15;
    const int r   = tid >> 2;
    const int c4  = (tid & 3) * 16;
    const unsigned short* vp = V + (size_t)(b * S_ + kt + r) * ldv + h * DK_ + c4;
    *(short8*)&t[r * 72 + c4]     = *(const short8*)vp;
    *(short8*)&t[r * 72 + c4 + 8] = *(const short8*)(vp + 8);
    __syncthreads();
    short8 o0, o1;
    #pragma unroll
    for (int e = 0; e < 8; e++) {
        o0[e] = (short)t[(c4 + e) * 72 + r];
        o1[e] = (short)t[(c4 + 8 + e) * 72 + r];
    }
    unsigned short* op = Vt + ((size_t)bh * DK_ + r) * S_ + kt + c4;
    *(short8*)op       = o0;
    *(short8*)(op + 8) = o1;
}

// ----------------------------------------------- MFMA flash attention ----
// R7-verified (99.8us, MfmaUtil 33%, 2 blocks/CU): 2 q-tiles per block;
// single-buffer staging; XCD-chunk swizzle (K/V of each bh pinned to one
// XCD's L2); softmax denominator on the MFMA pipe (ones-fragment rowsum).
// LDS MUST stay <= ~36 KB: blocks stop co-residing between 35.8 and 51.7
// KB (R10/R11 regressions; schedulable multi-WG LDS budget < 160 KB).
#define ATK   64
#define KS_LD 64
#define PS_LD 72
#define NT_   (S_ / ATK)   // 32

__global__ __launch_bounds__(256)
void attn_mfma(const unsigned short* __restrict__ QKV,  // q @+0, k @+1024, stride QKVLD
               const unsigned short* __restrict__ Vt,   // [bh][dk][S]
               const int* __restrict__ mask,
               unsigned short* __restrict__ ctx)
{
    __shared__ unsigned short Ks[ATK * KS_LD];     // 8 KB  [key][dk]
    __shared__ unsigned short Vts[DK_ * KS_LD];    // 8 KB  [dk][key]
    __shared__ unsigned short Ps[4][32 * PS_LD];   // 18 KB [q][key] per wave
    __shared__ float maskadd[ATK];

    const int tid  = threadIdx.x;
    const int lane = tid & 63;
    const int w    = tid >> 6;
    const int c    = lane & 15;
    const int qd   = lane >> 4;

    // grid (8, 64) = 512 blocks; 64 logicals per XCD = 8 bh-groups
    const int flat    = blockIdx.y * gridDim.x + blockIdx.x;
    const int logical = (flat & 7) * 64 + (flat >> 3);
    const int bh   = logical >> 3;
    const int b    = bh >> 4;
    const int h    = bh & 15;
    const int qb   = (logical & 7) * 256 + w * 32;   // qh=0 base; qh=1: +128

    const int lrow = lane >> 3;                   // 0..7
    const int swz  = ((lane & 7) ^ lrow) * 8;     // swizzled global col chunk
    const int cx   = c & 7;

    // all-ones bf16 B-fragment for the rowsum MFMA
    short8 onesf;
    #pragma unroll
    for (int e = 0; e < 8; e++) onesf[e] = (short)0x3F80;

    // Q fragments for both q-halves (B operand), pre-scaled by log2(e)/8
    const float QS = 0.18033688f;
    short8 qf[2][2][2];   // [qh][jq][kk]
    #pragma unroll
    for (int qh = 0; qh < 2; qh++)
        #pragma unroll
        for (int jq = 0; jq < 2; jq++)
            #pragma unroll
            for (int kk = 0; kk < 2; kk++) {
                const unsigned short* qp =
                    QKV + (size_t)(b * S_ + qb + qh * 128 + jq * 16 + c) * QKVLD
                        + h * DK_ + kk * 32 + qd * 8;
                short8 t = *(const short8*)qp;
                short8 o;
                #pragma unroll
                for (int e = 0; e < 8; e++)
                    o[e] = (short)f2bf(bf2f((unsigned short)t[e]) * QS);
                qf[qh][jq][kk] = o;
            }

    floatx4 acc_o[2][2][4];   // [qh][iq][jd]
    floatx4 acc_l[2][2];      // [qh][iq]  rowsum(P)
    #pragma unroll
    for (int qh = 0; qh < 2; qh++) {
        #pragma unroll
        for (int iq = 0; iq < 2; iq++) {
            acc_l[qh][iq] = (floatx4){0.f, 0.f, 0.f, 0.f};
            #pragma unroll
            for (int jd = 0; jd < 4; jd++)
                acc_o[qh][iq][jd] = (floatx4){0.f, 0.f, 0.f, 0.f};
        }
    }

    for (int kt = 0; kt < S_; kt += ATK) {
        // async staging (swizzled): wave w covers rows w*16 .. w*16+15
        {
            const unsigned short* kbase =
                QKV + 1024 + (size_t)(b * S_ + kt + w * 16) * QKVLD + h * DK_;
            const unsigned short* vbase =
                Vt + ((size_t)bh * DK_ + w * 16) * S_ + kt;
            #pragma unroll
            for (int t = 0; t < 2; t++) {
                async_cp16(kbase + (size_t)(t * 8 + lrow) * QKVLD + swz,
                           &Ks[(w * 16 + t * 8) * KS_LD]);
                async_cp16(vbase + (size_t)(t * 8 + lrow) * S_ + swz,
                           &Vts[(w * 16 + t * 8) * KS_LD]);
            }
            if (tid < ATK) maskadd[tid] = (mask[b * S_ + kt + tid] == 0) ? -1e9f : 0.f;
        }
        __syncthreads();

        #pragma unroll
        for (int qh = 0; qh < 2; qh++) {
            // scores^T (exp2 domain): key = i*16 + qd*4 + r, query = jq*16 + c
            floatx4 acc_s[4][2];
            #pragma unroll
            for (int i = 0; i < 4; i++)
                #pragma unroll
                for (int jq = 0; jq < 2; jq++)
                    acc_s[i][jq] = (floatx4){0.f, 0.f, 0.f, 0.f};
            #pragma unroll
            for (int kk = 0; kk < 2; kk++) {
                const int pos = ((kk * 4 + qd) ^ cx) * 8;
                short8 kf[4];
                #pragma unroll
                for (int i = 0; i < 4; i++)
                    kf[i] = *(const short8*)&Ks[(i * 16 + c) * KS_LD + pos];
                __builtin_amdgcn_s_setprio(1);
                #pragma unroll
                for (int i = 0; i < 4; i++)
                    #pragma unroll
                    for (int jq = 0; jq < 2; jq++)
                        acc_s[i][jq] = __builtin_amdgcn_mfma_f32_16x16x32_bf16(
                                           kf[i], qf[qh][jq][kk], acc_s[i][jq], 0, 0, 0);
                __builtin_amdgcn_s_setprio(0);
            }

            floatx4 madd[4];
            #pragma unroll
            for (int i = 0; i < 4; i++)
                madd[i] = *(const floatx4*)&maskadd[i * 16 + qd * 4];

            #pragma unroll
            for (int jq = 0; jq < 2; jq++) {
                #pragma unroll
                for (int i = 0; i < 4; i++) {
                    floatx4 p;
                    #pragma unroll
                    for (int r = 0; r < 4; r++)
                        p[r] = __builtin_amdgcn_exp2f(acc_s[i][jq][r] + madd[i][r]);
                    unsigned int w0, w1;
                    asm("v_cvt_pk_bf16_f32 %0, %1, %2" : "=v"(w0) : "v"(p[0]), "v"(p[1]));
                    asm("v_cvt_pk_bf16_f32 %0, %1, %2" : "=v"(w1) : "v"(p[2]), "v"(p[3]));
                    uint2 pk; pk.x = w0; pk.y = w1;
                    *(uint2*)&Ps[w][(jq * 16 + c) * PS_LD + i * 16 + qd * 4] = pk;
                }
            }

            // PV: A=P (wave-private padded LDS), B=Vt (swizzled LDS);
            // acc_l accumulates rowsum(P) via ones-fragment MFMA
            #pragma unroll
            for (int kk = 0; kk < 2; kk++) {
                const int pos = ((kk * 4 + qd) ^ cx) * 8;
                short8 pf[2], vf[4];
                #pragma unroll
                for (int iq = 0; iq < 2; iq++)
                    pf[iq] = *(const short8*)&Ps[w][(iq * 16 + c) * PS_LD + kk * 32 + qd * 8];
                #pragma unroll
                for (int jd = 0; jd < 4; jd++)
                    vf[jd] = *(const short8*)&Vts[(jd * 16 + c) * KS_LD + pos];
                __builtin_amdgcn_s_setprio(1);
                #pragma unroll
                for (int iq = 0; iq < 2; iq++) {
                    #pragma unroll
                    for (int jd = 0; jd < 4; jd++)
                        acc_o[qh][iq][jd] = __builtin_amdgcn_mfma_f32_16x16x32_bf16(
                                                pf[iq], vf[jd], acc_o[qh][iq][jd], 0, 0, 0);
                    acc_l[qh][iq] = __builtin_amdgcn_mfma_f32_16x16x32_bf16(
                                        pf[iq], onesf, acc_l[qh][iq], 0, 0, 0);
                }
                __builtin_amdgcn_s_setprio(0);
            }
        }
        __syncthreads();
    }

    #pragma unroll
    for (int qh = 0; qh < 2; qh++)
        #pragma unroll
        for (int iq = 0; iq < 2; iq++) {
            floatx4 inv;
            #pragma unroll
            for (int r = 0; r < 4; r++) inv[r] = 1.f / acc_l[qh][iq][r];
            #pragma unroll
            for (int jd = 0; jd < 4; jd++)
                #pragma unroll
                for (int r = 0; r < 4; r++) {
                    const int row = qb + qh * 128 + iq * 16 + qd * 4 + r;
                    const int col = h * DK_ + jd * 16 + c;
                    ctx[(size_t)(b * S_ + row) * D_ + col] =
                        f2bf(acc_o[qh][iq][jd][r] * inv[r]);
                }
        }
}

// ---------------------------------------------------------------- launch --
extern "C" void kernel_launch(void* const* d_in, const int* in_sizes, int n_in,
                              void* d_out, int out_size, void* d_ws, size_t ws_size,
                              hipStream_t stream)
{
    const void* x_raw  = d_in[0];
    const int*  mask   = (const int*)d_in[1];
    const void* wq_raw = d_in[2];
    const void* wk_raw = d_in[3];
    const void* wv_raw = d_in[4];
    const void* wo_raw = d_in[5];
    const void* w1_raw = d_in[6];
    const void* b1_raw = d_in[7];
    const void* w2_raw = d_in[8];
    const void* b2_raw = d_in[9];
    const void* g1_raw = d_in[10];
    const void* be1_raw= d_in[11];
    const void* g2_raw = d_in[12];
    const void* be2_raw= d_in[13];

    char* ws = (char*)d_ws;
    const size_t MB = 1024 * 1024;
    int* flag = (int*)ws;
    unsigned short* cb1  = (unsigned short*)(ws + 1 * 1024);
    unsigned short* cb2  = (unsigned short*)(ws + 16 * 1024);
    unsigned short* cg1  = (unsigned short*)(ws + 32 * 1024);
    unsigned short* cbe1 = (unsigned short*)(ws + 40 * 1024);
    unsigned short* cg2  = (unsigned short*)(ws + 48 * 1024);
    unsigned short* cbe2 = (unsigned short*)(ws + 56 * 1024);
    unsigned short* cwqkvo = (unsigned short*)(ws + 1 * MB);
    unsigned short* cwqkv  = cwqkvo;
    unsigned short* cwo    = cwqkvo + 3 * (D_ * D_);
    unsigned short* cw1  = (unsigned short*)(ws + 9 * MB);
    unsigned short* cw2  = (unsigned short*)(ws + 17 * MB);
    unsigned short* xn1  = (unsigned short*)(ws + 25 * MB);
    unsigned short* ctx  = (unsigned short*)(ws + 25 * MB);
    unsigned short* zbuf = (unsigned short*)(ws + 25 * MB);
    unsigned short* qkv  = (unsigned short*)(ws + 41 * MB);
    float*          h1   = (float*)(ws + 57 * MB);
    unsigned short* vt   = (unsigned short*)d_out;
    unsigned short* xn2  = (unsigned short*)d_out;

    probe_small<<<1, 256, 0, stream>>>((const unsigned short*)x_raw, flag,
                                       b1_raw, b2_raw, g1_raw, be1_raw, g2_raw, be2_raw,
                                       cb1, cb2, cg1, cbe1, cg2, cbe2);
    cvt_all<<<6144, 256, 0, stream>>>(wq_raw, wk_raw, wv_raw, wo_raw, w1_raw, w2_raw,
                                      cwqkvo, cw1, cw2, flag);

    const dim3 blk(256);
    const dim3 blk5(512);
    const dim3 gs(D_ / BN, MTOT / BM);          // (8, 64)   128x128 grid
    const dim3 gsq(QKVLD / BN, MTOT / BM);      // (24, 64)  128x128 qkv grid, 1536 = 6/CU
    const dim3 gf256(2048 / GBN, MTOT / GBM);   // (8, 32)   256x256 grid, 256 = 1/CU

    ln_kernel<2><<<MTOT, blk, 0, stream>>>(x_raw, cg1, cbe1, xn1, flag);
    gemm_bt<0,0,0,0><<<gsq, blk, 0, stream>>>(xn1, D_, cwqkv, D_, nullptr, nullptr, qkv, MTOT, QKVLD, D_, flag);
    vtrans<<<dim3(S_ / 64, B_ * H_), blk, 0, stream>>>(qkv + 2048, QKVLD, vt);
    attn_mfma<<<dim3(S_ / 256, B_ * H_), blk, 0, stream>>>(qkv, vt, mask, ctx);
    gemm_bt<0,0,3,1><<<gs, blk, 0, stream>>>(ctx, D_, cwo, D_, nullptr, x_raw, h1, MTOT, D_, D_, flag);
    ln_kernel<1><<<MTOT, blk, 0, stream>>>(h1, cg2, cbe2, xn2, flag);
    gemm256_bt<1,1><<<gf256, blk5, 0, stream>>>(xn2, D_, cw1, D_, cb1, zbuf, MTOT, 2048, D_);
    gemm_bt<0,0,2,1><<<gs, blk, 0, stream>>>(zbuf, 2048, cw2, DFF_, nullptr, h1, h1, MTOT, D_, 2048, flag);
    const unsigned short* w1c = cw1 + (size_t)2048 * D_;
    gemm256_bt<1,1><<<gf256, blk5, 0, stream>>>(xn2, D_, w1c, D_, cb1 + 2048, zbuf, MTOT, 2048, D_);
    gemm_bt<0,1,2,2><<<gs, blk, 0, stream>>>(zbuf, 2048, cw2 + 2048, DFF_, cb2, h1, d_out, MTOT, D_, 2048, flag);
}

// Round 15
// 534.142 us; speedup vs baseline: 1.0220x; 1.0220x over previous
//
#include <hip/hip_runtime.h>
#include <hip/hip_bf16.h>
#include <cstdint>
#include <cstddef>

typedef __attribute__((ext_vector_type(8))) short short8;
typedef __attribute__((ext_vector_type(4))) float floatx4;
typedef __attribute__((ext_vector_type(4))) unsigned short ushort4e;

#define B_   4
#define S_   2048
#define D_   1024
#define H_   16
#define DK_  64
#define DFF_ 4096
#define MTOT (B_ * S_)   // 8192
#define QKVLD 3072       // fused qkv row stride

__device__ __forceinline__ float bf2f(unsigned short u) {
    union { unsigned int i; float f; } v; v.i = ((unsigned int)u) << 16; return v.f;
}
__device__ __forceinline__ unsigned short f2bf(float f) {
    union { float f; unsigned int i; } v; v.f = f;
    unsigned int u = v.i;
    u += 0x7fffu + ((u >> 16) & 1u);   // RNE
    return (unsigned short)(u >> 16);
}
__device__ __forceinline__ void async_cp16(const void* g, void* l) {
    __builtin_amdgcn_global_load_lds(
        (const __attribute__((address_space(1))) unsigned int*)g,
        (__attribute__((address_space(3))) unsigned int*)l,
        16, 0, 0);
}
__device__ __forceinline__ void gbar() {
    asm volatile("" ::: "memory");
    __builtin_amdgcn_s_barrier();
    asm volatile("" ::: "memory");
}

__device__ __forceinline__ void cvt8(const void* src, unsigned short* dst, int i, int fl) {
    if (fl) {
        const floatx4* s = (const floatx4*)src;
        floatx4 a = s[i * 2], b = s[i * 2 + 1];
        short8 o;
        o[0] = (short)f2bf(a[0]); o[1] = (short)f2bf(a[1]);
        o[2] = (short)f2bf(a[2]); o[3] = (short)f2bf(a[3]);
        o[4] = (short)f2bf(b[0]); o[5] = (short)f2bf(b[1]);
        o[6] = (short)f2bf(b[2]); o[7] = (short)f2bf(b[3]);
        ((short8*)dst)[i] = o;
    } else {
        ((short8*)dst)[i] = ((const short8*)src)[i];
    }
}

// --------------------------- merged dtype probe + small-tensor convert ----
// Single block: probe reduction -> barrier -> convert (flag via LDS).
__global__ void probe_small(const unsigned short* __restrict__ x, int* flag,
                            const void* b1, const void* b2, const void* g1,
                            const void* be1, const void* g2, const void* be2,
                            unsigned short* db1, unsigned short* db2, unsigned short* dg1,
                            unsigned short* dbe1, unsigned short* dg2, unsigned short* dbe2) {
    __shared__ float red[4];
    __shared__ int flagS;
    const int tid = threadIdx.x;
    float mx = 0.f;
    #pragma unroll
    for (int i = 0; i < 16; i++) {
        float v = fabsf(bf2f(x[tid * 16 + i]));
        if (v != v) v = 1e30f;
        mx = fmaxf(mx, v);
    }
    #pragma unroll
    for (int off = 32; off > 0; off >>= 1) mx = fmaxf(mx, __shfl_down(mx, off));
    if ((tid & 63) == 0) red[tid >> 6] = mx;
    __syncthreads();
    if (tid == 0) {
        float m = fmaxf(fmaxf(red[0], red[1]), fmaxf(red[2], red[3]));
        int f = (m > 50.f) ? 1 : 0;
        *flag = f;
        flagS = f;
    }
    __syncthreads();
    const int fl = flagS;
    for (int i = tid; i < 1152; i += 256) {
        if (i < 512)       cvt8(b1,  db1,  i,        fl);
        else if (i < 640)  cvt8(b2,  db2,  i - 512,  fl);
        else if (i < 768)  cvt8(g1,  dg1,  i - 640,  fl);
        else if (i < 896)  cvt8(be1, dbe1, i - 768,  fl);
        else if (i < 1024) cvt8(g2,  dg2,  i - 896,  fl);
        else               cvt8(be2, dbe2, i - 1024, fl);
    }
}

// --------------------------------- merged weight convert (qkvo+w1+w2) ----
// 6144 blocks: [0,2048) qkvo (4 x D*D), [2048,4096) w1, [4096,6144) w2.
__global__ void cvt_all(const void* s0, const void* s1, const void* s2, const void* s3,
                        const void* w1, const void* w2,
                        unsigned short* __restrict__ dq,
                        unsigned short* __restrict__ dw1,
                        unsigned short* __restrict__ dw2,
                        const int* __restrict__ flag) {
    const int bid = blockIdx.x;
    const int fl  = *flag;
    if (bid < 2048) {
        const int t = bid >> 9;
        const int i = (bid & 511) * 256 + threadIdx.x;
        const void* s = (t == 0) ? s0 : (t == 1) ? s1 : (t == 2) ? s2 : s3;
        cvt8(s, dq + (size_t)t * (D_ * D_), i, fl);
    } else if (bid < 4096) {
        const int i = (bid - 2048) * 256 + threadIdx.x;
        cvt8(w1, dw1, i, fl);
    } else {
        const int i = (bid - 4096) * 256 + threadIdx.x;
        cvt8(w2, dw2, i, fl);
    }
}

// ---------------------------------------------------------------- GEMM ----
// 128x128 kernel (wo / ffn2).  XCD-chunk swizzle: contiguous by-rows per
// XCD so each XCD's weight panel set stays L2-resident.
#define BM 128
#define BN 128
#define BK 64

template<int RELU, int HAS_BIAS, int RES_MODE, int OUT_MODE>
__global__ __launch_bounds__(256)
void gemm_bt(const unsigned short* __restrict__ A, int lda,
             const unsigned short* __restrict__ W, int ldw,
             const unsigned short* __restrict__ bias,
             const void* resid,
             void* out,
             int M, int N, int K,
             const int* __restrict__ flagp)
{
    __shared__ unsigned short As[BM * BK];
    __shared__ unsigned short Bs[BN * BK];

    const int tid  = threadIdx.x;
    const int lane = tid & 63;
    const int wave = tid >> 6;
    const int wm = wave >> 1;
    const int wn = wave & 1;
    const int lr = lane & 15;
    const int lq = lane >> 4;

    // bijective XCD-chunk swizzle (nwg % 8 == 0 for all call sites)
    const int nwg     = gridDim.x * gridDim.y;
    const int flat    = blockIdx.y * gridDim.x + blockIdx.x;
    const int logical = (flat & 7) * (nwg >> 3) + (flat >> 3);
    const int m0 = (logical / gridDim.x) * BM;
    const int n0 = (logical % gridDim.x) * BN;

    int fl = 1;
    if (RES_MODE == 3 || OUT_MODE == 2) fl = *flagp;

    floatx4 acc[4][4];
    #pragma unroll
    for (int i = 0; i < 4; i++)
        #pragma unroll
        for (int j = 0; j < 4; j++)
            acc[i][j] = (floatx4){0.f, 0.f, 0.f, 0.f};

    const int lrow = lane >> 3;                       // 0..7
    const int swz  = ((lane & 7) ^ lrow) * 8;         // swizzled col chunk
    const int rx   = lr & 7;
    const int p0   = ((lq)     ^ rx) * 8;             // kk=0 chunk = lq
    const int p1   = ((4 + lq) ^ rx) * 8;             // kk=32 chunk = 4+lq

    for (int k0 = 0; k0 < K; k0 += BK) {
        #pragma unroll
        for (int t = 0; t < 4; t++) {
            const int row = wave * 32 + t * 8;
            async_cp16(A + (size_t)(m0 + row + lrow) * lda + k0 + swz, &As[row * BK]);
            async_cp16(W + (size_t)(n0 + row + lrow) * ldw + k0 + swz, &Bs[row * BK]);
        }
        __syncthreads();
        #pragma unroll
        for (int kk = 0; kk < 2; kk++) {
            const int pos = kk ? p1 : p0;
            short8 af[4], bfr[4];
            #pragma unroll
            for (int i = 0; i < 4; i++) {
                af[i]  = *(const short8*)(&As[(wm * 64 + i * 16 + lr) * BK + pos]);
                bfr[i] = *(const short8*)(&Bs[(wn * 64 + i * 16 + lr) * BK + pos]);
            }
            #pragma unroll
            for (int i = 0; i < 4; i++)
                #pragma unroll
                for (int j = 0; j < 4; j++)
                    acc[i][j] = __builtin_amdgcn_mfma_f32_16x16x32_bf16(
                                    af[i], bfr[j], acc[i][j], 0, 0, 0);
        }
        __syncthreads();
    }

    #pragma unroll
    for (int i = 0; i < 4; i++) {
        #pragma unroll
        for (int j = 0; j < 4; j++) {
            const int col = n0 + wn * 64 + j * 16 + lr;
            const float bv = HAS_BIAS ? bf2f(bias[col]) : 0.f;
            #pragma unroll
            for (int r = 0; r < 4; r++) {
                const int row = m0 + wm * 64 + i * 16 + lq * 4 + r;
                const size_t idx = (size_t)row * N + col;
                float vvv = acc[i][j][r] + bv;
                if (RES_MODE == 1) vvv += bf2f(((const unsigned short*)resid)[idx]);
                if (RES_MODE == 2) vvv += ((const float*)resid)[idx];
                if (RES_MODE == 3) vvv += fl ? ((const float*)resid)[idx]
                                             : bf2f(((const unsigned short*)resid)[idx]);
                if (RELU) vvv = fmaxf(vvv, 0.f);
                if (OUT_MODE == 1)      ((float*)out)[idx] = vvv;
                else if (OUT_MODE == 0) ((unsigned short*)out)[idx] = f2bf(vvv);
                else { if (fl) ((float*)out)[idx] = vvv;
                       else    ((unsigned short*)out)[idx] = f2bf(vvv); }
            }
        }
    }
}

// -------------------------------------------- 256x256 GEMM (qkv / ffn1) --
// R7-verified configuration.
#define GBM 256
#define GBN 256
#define GBK 64

template<int RELU, int HAS_BIAS>
__global__ __launch_bounds__(512, 2)
void gemm256_bt(const unsigned short* __restrict__ A, int lda,
                const unsigned short* __restrict__ W, int ldw,
                const unsigned short* __restrict__ bias,
                unsigned short* __restrict__ out,
                int M, int N, int K)
{
    __shared__ unsigned short As[2][GBM * GBK];   // 64 KB
    __shared__ unsigned short Bs[2][GBN * GBK];   // 64 KB

    const int tid  = threadIdx.x;
    const int lane = tid & 63;
    const int wave = tid >> 6;       // 0..7
    const int wm   = wave >> 2;      // 0..1  -> rows wm*128
    const int wn   = wave & 3;       // 0..3  -> cols wn*64
    const int lr   = lane & 15;
    const int lq   = lane >> 4;

    // bijective XCD-chunk swizzle (nwg = 384 or 256, both % 8 == 0)
    const int nwg     = gridDim.x * gridDim.y;
    const int flat    = blockIdx.y * gridDim.x + blockIdx.x;
    const int logical = (flat & 7) * (nwg >> 3) + (flat >> 3);
    const int m0 = (logical / gridDim.x) * GBM;
    const int n0 = (logical % gridDim.x) * GBN;

    const int lrow = lane >> 3;                   // 0..7
    const int schk = ((lane & 7) ^ lrow) * 8;     // pre-swizzled source chunk
    const int rx   = lr & 7;
    const int fp0  = ((lq)     ^ rx) * 8;         // kk=0 frag chunk
    const int fp1  = ((4 + lq) ^ rx) * 8;         // kk=32 frag chunk

    floatx4 acc[8][4];
    #pragma unroll
    for (int i = 0; i < 8; i++)
        #pragma unroll
        for (int j = 0; j < 4; j++)
            acc[i][j] = (floatx4){0.f, 0.f, 0.f, 0.f};

    const int nkt = K / GBK;

    // prologue: stage tile 0 into buffer 0, full drain (once)
    #pragma unroll
    for (int g = 0; g < 4; g++) {
        async_cp16(A + (size_t)(m0 + g * 64 + wave * 8 + lrow) * lda + schk,
                   &As[0][g * 4096 + wave * 512]);
        async_cp16(W + (size_t)(n0 + g * 64 + wave * 8 + lrow) * ldw + schk,
                   &Bs[0][g * 4096 + wave * 512]);
    }
    asm volatile("s_waitcnt vmcnt(0)" ::: "memory");
    __syncthreads();

    for (int t = 0; t < nkt; ++t) {
        const int cur   = t & 1;
        const int knext = (t + 1) * GBK;
        const bool more = (t + 1 < nkt);
        short8 bfr[4][2];

        #pragma unroll
        for (int p = 0; p < 4; ++p) {
            short8 af[2][2];
            #pragma unroll
            for (int ii = 0; ii < 2; ii++)
                #pragma unroll
                for (int kk = 0; kk < 2; kk++)
                    af[ii][kk] = *(const short8*)
                        &As[cur][(wm * 128 + p * 32 + ii * 16 + lr) * GBK + (kk ? fp1 : fp0)];
            if (p == 0) {
                #pragma unroll
                for (int j = 0; j < 4; j++)
                    #pragma unroll
                    for (int kk = 0; kk < 2; kk++)
                        bfr[j][kk] = *(const short8*)
                            &Bs[cur][(wn * 64 + j * 16 + lr) * GBK + (kk ? fp1 : fp0)];
                if (more) {
                    #pragma unroll
                    for (int g = 0; g < 4; g++)
                        async_cp16(A + (size_t)(m0 + g * 64 + wave * 8 + lrow) * lda + knext + schk,
                                   &As[cur ^ 1][g * 4096 + wave * 512]);
                }
            }
            if (p == 1 && more) {
                #pragma unroll
                for (int g = 0; g < 4; g++)
                    async_cp16(W + (size_t)(n0 + g * 64 + wave * 8 + lrow) * ldw + knext + schk,
                               &Bs[cur ^ 1][g * 4096 + wave * 512]);
            }
            if (p == 3) asm volatile("s_waitcnt vmcnt(0)" ::: "memory");
            gbar();
            __builtin_amdgcn_s_setprio(1);
            #pragma unroll
            for (int kk = 0; kk < 2; kk++)
                #pragma unroll
                for (int ii = 0; ii < 2; ii++)
                    #pragma unroll
                    for (int j = 0; j < 4; j++)
                        acc[p * 2 + ii][j] = __builtin_amdgcn_mfma_f32_16x16x32_bf16(
                                                 af[ii][kk], bfr[j][kk],
                                                 acc[p * 2 + ii][j], 0, 0, 0);
            __builtin_amdgcn_s_setprio(0);
            gbar();
        }
    }

    #pragma unroll
    for (int i = 0; i < 8; i++) {
        #pragma unroll
        for (int j = 0; j < 4; j++) {
            const int col = n0 + wn * 64 + j * 16 + lr;
            const float bv = HAS_BIAS ? bf2f(bias[col]) : 0.f;
            #pragma unroll
            for (int r = 0; r < 4; r++) {
                const int row = m0 + wm * 128 + i * 16 + lq * 4 + r;
                float vvv = acc[i][j][r] + bv;
                if (RELU) vvv = fmaxf(vvv, 0.f);
                out[(size_t)row * N + col] = f2bf(vvv);
            }
        }
    }
}

// ------------------------------------------------------------- LayerNorm --
template<int IN_MODE>   // 1 = f32, 2 = flag ? f32 : bf16
__global__ __launch_bounds__(256)
void ln_kernel(const void* __restrict__ Xv,
               const unsigned short* __restrict__ g,
               const unsigned short* __restrict__ be,
               unsigned short* __restrict__ out,
               const int* __restrict__ flagp)
{
    const int row = blockIdx.x;
    const int tid = threadIdx.x;
    int fl = 1;
    if (IN_MODE == 2) fl = *flagp;
    float x4[4];
    if (IN_MODE == 1 || fl) {
        const float* X = (const float*)Xv + (size_t)row * D_ + tid * 4;
        floatx4 t = *(const floatx4*)X;
        x4[0] = t[0]; x4[1] = t[1]; x4[2] = t[2]; x4[3] = t[3];
    } else {
        const unsigned short* X = (const unsigned short*)Xv + (size_t)row * D_ + tid * 4;
        ushort4e u = *(const ushort4e*)X;
        #pragma unroll
        for (int i = 0; i < 4; i++) x4[i] = bf2f(u[i]);
    }
    float s1 = x4[0] + x4[1] + x4[2] + x4[3];
    float s2 = x4[0]*x4[0] + x4[1]*x4[1] + x4[2]*x4[2] + x4[3]*x4[3];
    #pragma unroll
    for (int off = 32; off > 0; off >>= 1) {
        s1 += __shfl_down(s1, off);
        s2 += __shfl_down(s2, off);
    }
    __shared__ float r1[4], r2[4];
    const int wv = tid >> 6;
    if ((tid & 63) == 0) { r1[wv] = s1; r2[wv] = s2; }
    __syncthreads();
    s1 = r1[0] + r1[1] + r1[2] + r1[3];
    s2 = r2[0] + r2[1] + r2[2] + r2[3];
    const float mean = s1 * (1.0f / D_);
    const float var  = (s2 - (float)D_ * mean * mean) * (1.0f / (D_ - 1));
    const float rstd = rsqrtf(var + 1e-9f);

    ushort4e o4;
    #pragma unroll
    for (int i = 0; i < 4; i++) {
        const float gv = bf2f(g[tid * 4 + i]);
        const float bv = bf2f(be[tid * 4 + i]);
        o4[i] = f2bf(gv * (x4[i] - mean) * rstd + bv);
    }
    *(ushort4e*)(out + (size_t)row * D_ + tid * 4) = o4;
}

// -------------------------------------------------- V transpose per head --
__global__ __launch_bounds__(256)
void vtrans(const unsigned short* __restrict__ V, int ldv,
            unsigned short* __restrict__ Vt)
{
    __shared__ unsigned short t[64 * 72];
    const int tid = threadIdx.x;
    const int kt  = blockIdx.x * 64;
    const int bh  = blockIdx.y;
    const int b   = bh >> 4, h = bh & 15;
    const int r   = tid >> 2;
    const int c4  = (tid & 3) * 16;
    const unsigned short* vp = V + (size_t)(b * S_ + kt + r) * ldv + h * DK_ + c4;
    *(short8*)&t[r * 72 + c4]     = *(const short8*)vp;
    *(short8*)&t[r * 72 + c4 + 8] = *(const short8*)(vp + 8);
    __syncthreads();
    short8 o0, o1;
    #pragma unroll
    for (int e = 0; e < 8; e++) {
        o0[e] = (short)t[(c4 + e) * 72 + r];
        o1[e] = (short)t[(c4 + 8 + e) * 72 + r];
    }
    unsigned short* op = Vt + ((size_t)bh * DK_ + r) * S_ + kt + c4;
    *(short8*)op       = o0;
    *(short8*)(op + 8) = o1;
}

// ----------------------------------------------- MFMA flash attention ----
// R7-verified (99.8us, MfmaUtil 33%, 2 blocks/CU): 2 q-tiles per block;
// single-buffer staging; XCD-chunk swizzle (K/V of each bh pinned to one
// XCD's L2); softmax denominator on the MFMA pipe (ones-fragment rowsum).
// LDS MUST stay <= ~36 KB: blocks stop co-residing between 35.8 and 51.7
// KB (R10/R11 regressions; schedulable multi-WG LDS budget < 160 KB).
#define ATK   64
#define KS_LD 64
#define PS_LD 72
#define NT_   (S_ / ATK)   // 32

__global__ __launch_bounds__(256)
void attn_mfma(const unsigned short* __restrict__ QKV,  // q @+0, k @+1024, stride QKVLD
               const unsigned short* __restrict__ Vt,   // [bh][dk][S]
               const int* __restrict__ mask,
               unsigned short* __restrict__ ctx)
{
    __shared__ unsigned short Ks[ATK * KS_LD];     // 8 KB  [key][dk]
    __shared__ unsigned short Vts[DK_ * KS_LD];    // 8 KB  [dk][key]
    __shared__ unsigned short Ps[4][32 * PS_LD];   // 18 KB [q][key] per wave
    __shared__ float maskadd[ATK];

    const int tid  = threadIdx.x;
    const int lane = tid & 63;
    const int w    = tid >> 6;
    const int c    = lane & 15;
    const int qd   = lane >> 4;

    // grid (8, 64) = 512 blocks; 64 logicals per XCD = 8 bh-groups
    const int flat    = blockIdx.y * gridDim.x + blockIdx.x;
    const int logical = (flat & 7) * 64 + (flat >> 3);
    const int bh   = logical >> 3;
    const int b    = bh >> 4;
    const int h    = bh & 15;
    const int qb   = (logical & 7) * 256 + w * 32;   // qh=0 base; qh=1: +128

    const int lrow = lane >> 3;                   // 0..7
    const int swz  = ((lane & 7) ^ lrow) * 8;     // swizzled global col chunk
    const int cx   = c & 7;

    // all-ones bf16 B-fragment for the rowsum MFMA
    short8 onesf;
    #pragma unroll
    for (int e = 0; e < 8; e++) onesf[e] = (short)0x3F80;

    // Q fragments for both q-halves (B operand), pre-scaled by log2(e)/8
    const float QS = 0.18033688f;
    short8 qf[2][2][2];   // [qh][jq][kk]
    #pragma unroll
    for (int qh = 0; qh < 2; qh++)
        #pragma unroll
        for (int jq = 0; jq < 2; jq++)
            #pragma unroll
            for (int kk = 0; kk < 2; kk++) {
                const unsigned short* qp =
                    QKV + (size_t)(b * S_ + qb + qh * 128 + jq * 16 + c) * QKVLD
                        + h * DK_ + kk * 32 + qd * 8;
                short8 t = *(const short8*)qp;
                short8 o;
                #pragma unroll
                for (int e = 0; e < 8; e++)
                    o[e] = (short)f2bf(bf2f((unsigned short)t[e]) * QS);
                qf[qh][jq][kk] = o;
            }

    floatx4 acc_o[2][2][4];   // [qh][iq][jd]
    floatx4 acc_l[2][2];      // [qh][iq]  rowsum(P)
    #pragma unroll
    for (int qh = 0; qh < 2; qh++) {
        #pragma unroll
        for (int iq = 0; iq < 2; iq++) {
            acc_l[qh][iq] = (floatx4){0.f, 0.f, 0.f, 0.f};
            #pragma unroll
            for (int jd = 0; jd < 4; jd++)
                acc_o[qh][iq][jd] = (floatx4){0.f, 0.f, 0.f, 0.f};
        }
    }

    for (int kt = 0; kt < S_; kt += ATK) {
        // async staging (swizzled): wave w covers rows w*16 .. w*16+15
        {
            const unsigned short* kbase =
                QKV + 1024 + (size_t)(b * S_ + kt + w * 16) * QKVLD + h * DK_;
            const unsigned short* vbase =
                Vt + ((size_t)bh * DK_ + w * 16) * S_ + kt;
            #pragma unroll
            for (int t = 0; t < 2; t++) {
                async_cp16(kbase + (size_t)(t * 8 + lrow) * QKVLD + swz,
                           &Ks[(w * 16 + t * 8) * KS_LD]);
                async_cp16(vbase + (size_t)(t * 8 + lrow) * S_ + swz,
                           &Vts[(w * 16 + t * 8) * KS_LD]);
            }
            if (tid < ATK) maskadd[tid] = (mask[b * S_ + kt + tid] == 0) ? -1e9f : 0.f;
        }
        __syncthreads();

        #pragma unroll
        for (int qh = 0; qh < 2; qh++) {
            // scores^T (exp2 domain): key = i*16 + qd*4 + r, query = jq*16 + c
            floatx4 acc_s[4][2];
            #pragma unroll
            for (int i = 0; i < 4; i++)
                #pragma unroll
                for (int jq = 0; jq < 2; jq++)
                    acc_s[i][jq] = (floatx4){0.f, 0.f, 0.f, 0.f};
            #pragma unroll
            for (int kk = 0; kk < 2; kk++) {
                const int pos = ((kk * 4 + qd) ^ cx) * 8;
                short8 kf[4];
                #pragma unroll
                for (int i = 0; i < 4; i++)
                    kf[i] = *(const short8*)&Ks[(i * 16 + c) * KS_LD + pos];
                __builtin_amdgcn_s_setprio(1);
                #pragma unroll
                for (int i = 0; i < 4; i++)
                    #pragma unroll
                    for (int jq = 0; jq < 2; jq++)
                        acc_s[i][jq] = __builtin_amdgcn_mfma_f32_16x16x32_bf16(
                                           kf[i], qf[qh][jq][kk], acc_s[i][jq], 0, 0, 0);
                __builtin_amdgcn_s_setprio(0);
            }

            floatx4 madd[4];
            #pragma unroll
            for (int i = 0; i < 4; i++)
                madd[i] = *(const floatx4*)&maskadd[i * 16 + qd * 4];

            #pragma unroll
            for (int jq = 0; jq < 2; jq++) {
                #pragma unroll
                for (int i = 0; i < 4; i++) {
                    floatx4 p;
                    #pragma unroll
                    for (int r = 0; r < 4; r++)
                        p[r] = __builtin_amdgcn_exp2f(acc_s[i][jq][r] + madd[i][r]);
                    unsigned int w0, w1;
                    asm("v_cvt_pk_bf16_f32 %0, %1, %2" : "=v"(w0) : "v"(p[0]), "v"(p[1]));
                    asm("v_cvt_pk_bf16_f32 %0, %1, %2" : "=v"(w1) : "v"(p[2]), "v"(p[3]));
                    uint2 pk; pk.x = w0; pk.y = w1;
                    *(uint2*)&Ps[w][(jq * 16 + c) * PS_LD + i * 16 + qd * 4] = pk;
                }
            }

            // PV: A=P (wave-private padded LDS), B=Vt (swizzled LDS);
            // acc_l accumulates rowsum(P) via ones-fragment MFMA
            #pragma unroll
            for (int kk = 0; kk < 2; kk++) {
                const int pos = ((kk * 4 + qd) ^ cx) * 8;
                short8 pf[2], vf[4];
                #pragma unroll
                for (int iq = 0; iq < 2; iq++)
                    pf[iq] = *(const short8*)&Ps[w][(iq * 16 + c) * PS_LD + kk * 32 + qd * 8];
                #pragma unroll
                for (int jd = 0; jd < 4; jd++)
                    vf[jd] = *(const short8*)&Vts[(jd * 16 + c) * KS_LD + pos];
                __builtin_amdgcn_s_setprio(1);
                #pragma unroll
                for (int iq = 0; iq < 2; iq++) {
                    #pragma unroll
                    for (int jd = 0; jd < 4; jd++)
                        acc_o[qh][iq][jd] = __builtin_amdgcn_mfma_f32_16x16x32_bf16(
                                                pf[iq], vf[jd], acc_o[qh][iq][jd], 0, 0, 0);
                    acc_l[qh][iq] = __builtin_amdgcn_mfma_f32_16x16x32_bf16(
                                        pf[iq], onesf, acc_l[qh][iq], 0, 0, 0);
                }
                __builtin_amdgcn_s_setprio(0);
            }
        }
        __syncthreads();
    }

    #pragma unroll
    for (int qh = 0; qh < 2; qh++)
        #pragma unroll
        for (int iq = 0; iq < 2; iq++) {
            floatx4 inv;
            #pragma unroll
            for (int r = 0; r < 4; r++) inv[r] = 1.f / acc_l[qh][iq][r];
            #pragma unroll
            for (int jd = 0; jd < 4; jd++)
                #pragma unroll
                for (int r = 0; r < 4; r++) {
                    const int row = qb + qh * 128 + iq * 16 + qd * 4 + r;
                    const int col = h * DK_ + jd * 16 + c;
                    ctx[(size_t)(b * S_ + row) * D_ + col] =
                        f2bf(acc_o[qh][iq][jd][r] * inv[r]);
                }
        }
}

// ---------------------------------------------------------------- launch --
extern "C" void kernel_launch(void* const* d_in, const int* in_sizes, int n_in,
                              void* d_out, int out_size, void* d_ws, size_t ws_size,
                              hipStream_t stream)
{
    const void* x_raw  = d_in[0];
    const int*  mask   = (const int*)d_in[1];
    const void* wq_raw = d_in[2];
    const void* wk_raw = d_in[3];
    const void* wv_raw = d_in[4];
    const void* wo_raw = d_in[5];
    const void* w1_raw = d_in[6];
    const void* b1_raw = d_in[7];
    const void* w2_raw = d_in[8];
    const void* b2_raw = d_in[9];
    const void* g1_raw = d_in[10];
    const void* be1_raw= d_in[11];
    const void* g2_raw = d_in[12];
    const void* be2_raw= d_in[13];

    char* ws = (char*)d_ws;
    const size_t MB = 1024 * 1024;
    int* flag = (int*)ws;
    unsigned short* cb1  = (unsigned short*)(ws + 1 * 1024);
    unsigned short* cb2  = (unsigned short*)(ws + 16 * 1024);
    unsigned short* cg1  = (unsigned short*)(ws + 32 * 1024);
    unsigned short* cbe1 = (unsigned short*)(ws + 40 * 1024);
    unsigned short* cg2  = (unsigned short*)(ws + 48 * 1024);
    unsigned short* cbe2 = (unsigned short*)(ws + 56 * 1024);
    unsigned short* cwqkvo = (unsigned short*)(ws + 1 * MB);
    unsigned short* cwqkv  = cwqkvo;
    unsigned short* cwo    = cwqkvo + 3 * (D_ * D_);
    unsigned short* cw1  = (unsigned short*)(ws + 9 * MB);
    unsigned short* cw2  = (unsigned short*)(ws + 17 * MB);
    unsigned short* xn1  = (unsigned short*)(ws + 25 * MB);
    unsigned short* ctx  = (unsigned short*)(ws + 25 * MB);
    unsigned short* zbuf = (unsigned short*)(ws + 25 * MB);
    unsigned short* qkv  = (unsigned short*)(ws + 41 * MB);
    float*          h1   = (float*)(ws + 57 * MB);
    unsigned short* vt   = (unsigned short*)d_out;
    unsigned short* xn2  = (unsigned short*)d_out;

    probe_small<<<1, 256, 0, stream>>>((const unsigned short*)x_raw, flag,
                                       b1_raw, b2_raw, g1_raw, be1_raw, g2_raw, be2_raw,
                                       cb1, cb2, cg1, cbe1, cg2, cbe2);
    cvt_all<<<6144, 256, 0, stream>>>(wq_raw, wk_raw, wv_raw, wo_raw, w1_raw, w2_raw,
                                      cwqkvo, cw1, cw2, flag);

    const dim3 blk(256);
    const dim3 blk5(512);
    const dim3 gs(D_ / BN, MTOT / BM);          // (8, 64)   128x128 grid
    const dim3 gq256(QKVLD / GBN, MTOT / GBM);  // (12, 32)  256x256 grid
    const dim3 gf256(2048 / GBN, MTOT / GBM);   // (8, 32)   256x256 grid

    ln_kernel<2><<<MTOT, blk, 0, stream>>>(x_raw, cg1, cbe1, xn1, flag);
    gemm256_bt<0,0><<<gq256, blk5, 0, stream>>>(xn1, D_, cwqkv, D_, nullptr, qkv, MTOT, QKVLD, D_);
    vtrans<<<dim3(S_ / 64, B_ * H_), blk, 0, stream>>>(qkv + 2048, QKVLD, vt);
    attn_mfma<<<dim3(S_ / 256, B_ * H_), blk, 0, stream>>>(qkv, vt, mask, ctx);
    gemm_bt<0,0,3,1><<<gs, blk, 0, stream>>>(ctx, D_, cwo, D_, nullptr, x_raw, h1, MTOT, D_, D_, flag);
    ln_kernel<1><<<MTOT, blk, 0, stream>>>(h1, cg2, cbe2, xn2, flag);
    gemm256_bt<1,1><<<gf256, blk5, 0, stream>>>(xn2, D_, cw1, D_, cb1, zbuf, MTOT, 2048, D_);
    gemm_bt<0,0,2,1><<<gs, blk, 0, stream>>>(zbuf, 2048, cw2, DFF_, nullptr, h1, h1, MTOT, D_, 2048, flag);
    const unsigned short* w1c = cw1 + (size_t)2048 * D_;
    gemm256_bt<1,1><<<gf256, blk5, 0, stream>>>(xn2, D_, w1c, D_, cb1 + 2048, zbuf, MTOT, 2048, D_);
    gemm_bt<0,1,2,2><<<gs, blk, 0, stream>>>(zbuf, 2048, cw2 + 2048, DFF_, cb2, h1, d_out, MTOT, D_, 2048, flag);
}